// Round 6
// baseline (1644.892 us; speedup 1.0000x reference)
//
#include <hip/hip_runtime.h>
#include <hip/hip_bf16.h>
#include <math.h>

// Problem constants
#define BB 4
#define CIN 64
#define DI 128       // D_INNER
#define NS 16        // D_STATE
#define HH 256
#define WW 256
#define HW 65536     // HH*WW (2^16)
#define NCH_P 33     // 1 + 2*NS

// ---------------------------------------------------------------- fast math helpers
__device__ __forceinline__ float softplusf(float x) {
    return fmaxf(x, 0.f) + __logf(1.0f + __expf(-fabsf(x)));
}
__device__ __forceinline__ float tanh_half(float a) {   // tanh(0.5*a)
    return 1.0f - 2.0f / (1.0f + __expf(a));
}
__device__ __forceinline__ float sigmoidf(float z) {
    return 1.0f / (1.0f + __expf(-z));
}

__device__ __forceinline__ void gauss15(float* g) {
    float s = 0.f;
#pragma unroll
    for (int i = 0; i < 15; ++i) {
        float a = (float)i - 7.0f;
        g[i] = __expf(-a * a / 18.0f);   // 2*sigma^2 = 18
        s += g[i];
    }
    float inv = 1.0f / s;
#pragma unroll
    for (int i = 0; i < 15; ++i) g[i] *= inv;
}

// ---------------------------------------------------------------- K1: in_proj (U half only), one batch
__global__ __launch_bounds__(256) void k_inproj(
    const float* __restrict__ xb, const float* __restrict__ w,
    const float* __restrict__ bias, float* __restrict__ Ub) {
    int p = blockIdx.x * 256 + threadIdx.x;
    int og = blockIdx.y * 64;
    float xv[CIN];
#pragma unroll
    for (int c = 0; c < CIN; ++c) xv[c] = xb[(size_t)c * HW + p];
#pragma unroll 2
    for (int o = og; o < og + 64; ++o) {
        float a0 = bias[o], a1 = 0.f, a2 = 0.f, a3 = 0.f;
        const float* wr = w + o * CIN;
#pragma unroll
        for (int c = 0; c < CIN; c += 4) {
            a0 = fmaf(xv[c],     wr[c],     a0);
            a1 = fmaf(xv[c + 1], wr[c + 1], a1);
            a2 = fmaf(xv[c + 2], wr[c + 2], a2);
            a3 = fmaf(xv[c + 3], wr[c + 3], a3);
        }
        Ub[(size_t)o * HW + p] = (a0 + a1) + (a2 + a3);
    }
}

// ---------------------------------------------------------------- K2: fused dw3x3+tanh+15x15 highpass, one batch
#define TILE_H 16
__global__ __launch_bounds__(256) void k_conv(
    const float* __restrict__ Ub, const float* __restrict__ dww,
    const float* __restrict__ dwb, float* __restrict__ Ucb) {
    __shared__ float sU[32 * 256];
    __shared__ float sC[30 * 272];
    int c  = blockIdx.x >> 4;
    int t  = blockIdx.x & 15;
    int h0 = t * TILE_H;
    int w  = threadIdx.x;

    const float* base = Ub + (size_t)c * HW;
#pragma unroll
    for (int i = 0; i < 32; ++i) {
        int hh = h0 + i - 8;
        sU[i * 256 + w] = (hh >= 0 && hh < HH) ? base[hh * WW + w] : 0.f;
    }
    __syncthreads();

    float wt[9];
#pragma unroll
    for (int i = 0; i < 9; ++i) wt[i] = dww[c * 9 + i];
    float bb = dwb[c];

#pragma unroll
    for (int i = 0; i < 30; ++i) {
        int r = h0 + i - 7;
        float v = 0.f;
        if (r >= 0 && r < HH) {
            float acc = bb;
#pragma unroll
            for (int ky = 0; ky < 3; ++ky) {
                const float* ur = sU + (i + ky) * 256;
#pragma unroll
                for (int kx = 0; kx < 3; ++kx) {
                    int ww = w + kx - 1;
                    if (ww >= 0 && ww < WW) acc = fmaf(ur[ww], wt[ky * 3 + kx], acc);
                }
            }
            v = tanh_half(acc);
        }
        sC[i * 272 + w + 7] = v;
    }
    if (w < 7) {
#pragma unroll
        for (int i = 0; i < 30; ++i) { sC[i * 272 + w] = 0.f; sC[i * 272 + w + 263] = 0.f; }
    }
    __syncthreads();

    float g[15]; gauss15(g);
#pragma unroll
    for (int i = 0; i < 30; ++i) {
        float acc = 0.f;
#pragma unroll
        for (int k = 0; k < 15; ++k) acc = fmaf(sC[i * 272 + w + k], g[k], acc);
        sU[i * 256 + w] = acc;
    }
    float* outp = Ucb + (size_t)c * HW + h0 * WW + w;
#pragma unroll
    for (int i = 0; i < TILE_H; ++i) {
        float acc = 0.f;
#pragma unroll
        for (int k = 0; k < 15; ++k) acc = fmaf(sU[(i + k) * 256 + w], g[k], acc);
        float center = sC[(i + 7) * 272 + w + 7];
        outp[i * WW] = center - acc;
    }
}

// ---------------------------------------------------------------- K5: x_proj (128 -> 33), nb batches
__global__ __launch_bounds__(256) void k_xproj(
    const float* __restrict__ Uc, const float* __restrict__ xw,
    float* __restrict__ P) {
    int p = blockIdx.x * 256 + threadIdx.x;
    int b = p >> 16;
    int rem = p & 65535;
    const float* up = Uc + (size_t)b * DI * HW + rem;
    float acc[NCH_P];
#pragma unroll
    for (int o = 0; o < NCH_P; ++o) acc[o] = 0.f;
    for (int c = 0; c < DI; ++c) {
        float u = up[(size_t)c * HW];
#pragma unroll
        for (int o = 0; o < NCH_P; ++o) acc[o] = fmaf(u, xw[o * DI + c], acc[o]);
    }
    float* pp = P + (size_t)b * NCH_P * HW + rem;
#pragma unroll
    for (int o = 0; o < NCH_P; ++o) pp[(size_t)o * HW] = acc[o];
}

// ---------------------------------------------------------------- K6: scan along W, LDS-staged u AND P, reg-prefetch
#define CW 32
__global__ __launch_bounds__(128) void k_scan_w(
    float* __restrict__ UY, const float* __restrict__ P,
    const float* __restrict__ A_log, const float* __restrict__ dtw,
    const float* __restrict__ dtb, const float* __restrict__ Dv) {
    __shared__ float sU[DI * 33];
    __shared__ float sP[CW * 36];
    int bh = blockIdx.x;
    int b = bh >> 8;
    int h = bh & 255;
    int t = threadIdx.x;                   // d

    float Av[NS];
#pragma unroll
    for (int n = 0; n < NS; ++n) Av[n] = -__expf(A_log[t * NS + n]);
    float wdt = dtw[t], bdt = dtb[t], Dd = Dv[t];
    float hS[NS];
#pragma unroll
    for (int n = 0; n < NS; ++n) hS[n] = 0.f;

    float* ubase = UY + (size_t)(b * DI) * HW + (size_t)h * WW;
    const float* prow = P + (size_t)(b * NCH_P) * HW + (size_t)h * WW;

    const int w4 = (t & 7) * 4;
    const int dbase = t >> 3;

    float4 rU[8];
    float rP[9];
#pragma unroll
    for (int p = 0; p < 8; ++p)
        rU[p] = *(const float4*)(ubase + (size_t)(dbase + p * 16) * HW + w4);
#pragma unroll
    for (int i = 0; i < 9; ++i) {
        int idx = i * 128 + t, ch = idx >> 5, wi = idx & 31;
        rP[i] = (ch < NCH_P) ? prow[(size_t)ch * HW + wi] : 0.f;
    }

    for (int w0 = 0; w0 < WW; w0 += CW) {
#pragma unroll
        for (int p = 0; p < 8; ++p) {
            float* s = sU + (dbase + p * 16) * 33 + w4;
            s[0] = rU[p].x; s[1] = rU[p].y; s[2] = rU[p].z; s[3] = rU[p].w;
        }
#pragma unroll
        for (int i = 0; i < 9; ++i) {
            int idx = i * 128 + t, ch = idx >> 5, wi = idx & 31;
            if (ch < NCH_P) sP[wi * 36 + ch] = rP[i];
        }
        __syncthreads();
        if (w0 + CW < WW) {
#pragma unroll
            for (int p = 0; p < 8; ++p)
                rU[p] = *(const float4*)(ubase + (size_t)(dbase + p * 16) * HW + w0 + CW + w4);
#pragma unroll
            for (int i = 0; i < 9; ++i) {
                int idx = i * 128 + t, ch = idx >> 5, wi = idx & 31;
                rP[i] = (ch < NCH_P) ? prow[(size_t)ch * HW + w0 + CW + wi] : 0.f;
            }
        }
#pragma unroll 2
        for (int wi = 0; wi < CW; ++wi) {
            const float* pr = sP + wi * 36;
            float4 q0 = *(const float4*)(pr);
            float4 q1 = *(const float4*)(pr + 4);
            float4 q2 = *(const float4*)(pr + 8);
            float4 q3 = *(const float4*)(pr + 12);
            float4 q4 = *(const float4*)(pr + 16);
            float4 q5 = *(const float4*)(pr + 20);
            float4 q6 = *(const float4*)(pr + 24);
            float4 q7 = *(const float4*)(pr + 28);
            float q8 = pr[32];
            float u = sU[t * 33 + wi];
            float dt = softplusf(fmaf(q0.x, wdt, bdt));
            float ud = u * dt;
            float y = Dd * u;
            float Bv[NS] = {q0.y,q0.z,q0.w,q1.x,q1.y,q1.z,q1.w,q2.x,
                            q2.y,q2.z,q2.w,q3.x,q3.y,q3.z,q3.w,q4.x};
            float Cv[NS] = {q4.y,q4.z,q4.w,q5.x,q5.y,q5.z,q5.w,q6.x,
                            q6.y,q6.z,q6.w,q7.x,q7.y,q7.z,q7.w,q8};
#pragma unroll
            for (int n = 0; n < NS; ++n) {
                float e = __expf(dt * Av[n]);
                hS[n] = fmaf(e, hS[n], ud * Bv[n]);
                y = fmaf(hS[n], Cv[n], y);
            }
            sU[t * 33 + wi] = y;
        }
        __syncthreads();
#pragma unroll
        for (int p = 0; p < 8; ++p) {
            const float* s = sU + (dbase + p * 16) * 33 + w4;
            float4 v; v.x = s[0]; v.y = s[1]; v.z = s[2]; v.w = s[3];
            *(float4*)(ubase + (size_t)(dbase + p * 16) * HW + w0 + w4) = v;
        }
        __syncthreads();
    }
}

// ---------------------------------------------------------------- K7: scan along H
// R2's known-good index form (262 us), unroll-8 with 8 u slots: u (HBM-streamed,
// ~900 cy) now prefetched 8 rows ahead; P (mostly L2 per FETCH arithmetic) stays
// at A/B distance-2. Copy-free static rotation. __launch_bounds__(256,1) grants
// the full 512-reg budget so the allocator neither spills (R1) nor AGPR-shuffles
// (R4). Live ~120 floats. Check: WRITE_SIZE must stay exactly 131072 KB.
#define PF_U(uu, hp_) { int hp = (hp_); if (hp > HH - 1) hp = HH - 1; \
    uu = ub[hp * WW + w]; }
#define PF_P(dde, Bp, Cp, hp_) { int hp = (hp_); if (hp > HH - 1) hp = HH - 1; \
    int off = hp * WW + w; dde = pb[off]; \
    _Pragma("unroll") for (int n = 0; n < NS; ++n) { \
        Bp[n] = pb[(1 + n) * HW + off]; Cp[n] = pb[(17 + n) * HW + off]; } }
#define ROW(hh, uu, dde, Bp, Cp) { \
    float dt = softplusf(fmaf(dde, wdt, bdt)); \
    float ud = uu * dt; \
    float y = Dd * uu; \
    _Pragma("unroll") for (int n = 0; n < NS; ++n) { \
        float e = __expf(dt * Av[n]); \
        hS[n] = fmaf(e, hS[n], ud * Bp[n]); \
        y = fmaf(hS[n], Cp[n], y); } \
    ub[(hh) * WW + w] = y; }

__global__ __launch_bounds__(256, 1) void k_scan_h(
    float* __restrict__ UY, const float* __restrict__ P,
    const float* __restrict__ A_log, const float* __restrict__ dtw,
    const float* __restrict__ dtb, const float* __restrict__ Dv) {
    int bd = blockIdx.x;
    int b = bd >> 7;
    int d = bd & (DI - 1);
    int w = threadIdx.x;
    float Av[NS];
#pragma unroll
    for (int n = 0; n < NS; ++n) Av[n] = -__expf(A_log[d * NS + n]);
    float wdt = dtw[d], bdt = dtb[d], Dd = Dv[d];
    float* ub = UY + (size_t)bd * HW;                 // uniform base
    const float* pb = P + (size_t)b * NCH_P * HW;     // uniform base
    float hS[NS];
#pragma unroll
    for (int n = 0; n < NS; ++n) hS[n] = 0.f;

    float u0, u1, u2, u3, u4, u5, u6, u7;
    float deA, deB;
    float BA[NS], CA[NS], Bb[NS], Cb[NS];

    PF_U(u0, 0); PF_U(u1, 1); PF_U(u2, 2); PF_U(u3, 3);
    PF_U(u4, 4); PF_U(u5, 5); PF_U(u6, 6); PF_U(u7, 7);
    PF_P(deA, BA, CA, 0);
    PF_P(deB, Bb, Cb, 1);

#pragma unroll 1
    for (int h = 0; h < HH; h += 8) {
        ROW(h,     u0, deA, BA, CA);  PF_P(deA, BA, CA, h + 2);  PF_U(u0, h + 8);
        ROW(h + 1, u1, deB, Bb, Cb);  PF_P(deB, Bb, Cb, h + 3);  PF_U(u1, h + 9);
        ROW(h + 2, u2, deA, BA, CA);  PF_P(deA, BA, CA, h + 4);  PF_U(u2, h + 10);
        ROW(h + 3, u3, deB, Bb, Cb);  PF_P(deB, Bb, Cb, h + 5);  PF_U(u3, h + 11);
        ROW(h + 4, u4, deA, BA, CA);  PF_P(deA, BA, CA, h + 6);  PF_U(u4, h + 12);
        ROW(h + 5, u5, deB, Bb, Cb);  PF_P(deB, Bb, Cb, h + 7);  PF_U(u5, h + 13);
        ROW(h + 6, u6, deA, BA, CA);  PF_P(deA, BA, CA, h + 8);  PF_U(u6, h + 14);
        ROW(h + 7, u7, deB, Bb, Cb);  PF_P(deB, Bb, Cb, h + 9);  PF_U(u7, h + 15);
    }
}

// ---------------------------------------------------------------- K8: fused gate + out projection (attempt 3)
// out[c] = sum_d Wo[c,d] * ( Y[d] * sigmoid(Wz[d,:]·x + bz[d]) ) + ob[c]
// R1 failed: (256,2) -> VGPR cap 128 -> scratch spill (WRITE_SIZE 20x).
// R4 failed: plain (256) -> default wave-target -> VGPR 76 + AGPR shuffle.
// Now (256,1): explicit 1-wave/EU floor -> full 512-reg budget; ~150 live floats
// should allocate cleanly. Success indicator: VGPR_Count >= 140 and
// WRITE_SIZE == 65536 KB. Arithmetic order identical to the split pair.
__global__ __launch_bounds__(256, 1) void k_gateout(
    const float* __restrict__ Y, const float* __restrict__ x,
    const float* __restrict__ wz, const float* __restrict__ bz,
    const float* __restrict__ ow, const float* __restrict__ ob,
    float* __restrict__ outp) {
    int p = blockIdx.x * 256 + threadIdx.x;
    int b = p >> 16;
    int rem = p & 65535;
    const float* xp = x + (size_t)b * CIN * HW + rem;
    const float* yp = Y + (size_t)b * DI * HW + rem;
    float xv[CIN];
#pragma unroll
    for (int c = 0; c < CIN; ++c) xv[c] = xp[(size_t)c * HW];
    float acc[CIN];
#pragma unroll
    for (int c = 0; c < CIN; ++c) acc[c] = 0.f;
#pragma unroll 2
    for (int dd = 0; dd < DI; ++dd) {
        const float* wr = wz + dd * CIN;
        float z0 = 0.f, z1 = 0.f, z2 = 0.f, z3 = 0.f;
#pragma unroll
        for (int c = 0; c < CIN; c += 4) {
            z0 = fmaf(xv[c],     wr[c],     z0);
            z1 = fmaf(xv[c + 1], wr[c + 1], z1);
            z2 = fmaf(xv[c + 2], wr[c + 2], z2);
            z3 = fmaf(xv[c + 3], wr[c + 3], z3);
        }
        float z = bz[dd] + ((z0 + z1) + (z2 + z3));
        float g = yp[(size_t)dd * HW] * sigmoidf(z);
#pragma unroll
        for (int c = 0; c < CIN; ++c) acc[c] = fmaf(g, ow[c * DI + dd], acc[c]);
    }
    float* op = outp + (size_t)b * CIN * HW + rem;
#pragma unroll
    for (int c = 0; c < CIN; ++c) op[(size_t)c * HW] = acc[c] + ob[c];
}

// ---------------------------------------------------------------- launch
extern "C" void kernel_launch(void* const* d_in, const int* in_sizes, int n_in,
                              void* d_out, int out_size, void* d_ws, size_t ws_size,
                              hipStream_t stream) {
    const float* x     = (const float*)d_in[0];
    const float* ipw   = (const float*)d_in[1];
    const float* ipb   = (const float*)d_in[2];
    const float* dww   = (const float*)d_in[3];
    const float* dwb   = (const float*)d_in[4];
    const float* xpw   = (const float*)d_in[5];
    const float* dtw   = (const float*)d_in[6];
    const float* dtb   = (const float*)d_in[7];
    const float* A_log = (const float*)d_in[8];
    const float* Dv    = (const float*)d_in[9];
    const float* ow    = (const float*)d_in[10];
    const float* ob    = (const float*)d_in[11];
    float* out = (float*)d_out;

    const float* wz = ipw + (size_t)DI * CIN;
    const float* bz = ipb + DI;

    const size_t PLANE = (size_t)DI * HW;
    const size_t NB    = (size_t)BB * PLANE;

    if (ws_size >= (NB + PLANE) * sizeof(float)) {
        // ---------- Path A: full-batch scans. ws = Y(4) + U(1); P staged in d_out.
        float* bufY = (float*)d_ws;
        float* bufU = bufY + NB;
        float* P    = out;
        for (int b = 0; b < BB; ++b) {
            k_inproj<<<dim3(HW / 256, 2), 256, 0, stream>>>(x + (size_t)b * CIN * HW, ipw, ipb, bufU);
            k_conv<<<DI * 16, 256, 0, stream>>>(bufU, dww, dwb, bufY + (size_t)b * PLANE);
        }
        k_xproj<<<BB * (HW / 256), 256, 0, stream>>>(bufY, xpw, P);
        k_scan_w<<<BB * HH, 128, 0, stream>>>(bufY, P, A_log, dtw, dtb, Dv);
        k_scan_h<<<BB * DI, 256, 0, stream>>>(bufY, P, A_log, dtw, dtb, Dv);
        k_gateout<<<BB * (HW / 256), 256, 0, stream>>>(bufY, x, wz, bz, ow, ob, out);
    } else {
        // ---------- Path B: batch-sequential. ws = U_b/P_b (overlapped) + Y_b.
        float* bufA = (float*)d_ws;
        float* bufY = bufA + PLANE;
        for (int b = 0; b < BB; ++b) {
            const float* xb = x + (size_t)b * CIN * HW;
            k_inproj<<<dim3(HW / 256, 2), 256, 0, stream>>>(xb, ipw, ipb, bufA);
            k_conv<<<DI * 16, 256, 0, stream>>>(bufA, dww, dwb, bufY);
            k_xproj<<<HW / 256, 256, 0, stream>>>(bufY, xpw, bufA);
            k_scan_w<<<HH, 128, 0, stream>>>(bufY, bufA, A_log, dtw, dtb, Dv);
            k_scan_h<<<DI, 256, 0, stream>>>(bufY, bufA, A_log, dtw, dtb, Dv);
            k_gateout<<<HW / 256, 256, 0, stream>>>(bufY, xb, wz, bz, ow, ob, out + (size_t)b * CIN * HW);
        }
    }
}

// Round 7
// 1463.258 us; speedup vs baseline: 1.1241x; 1.1241x over previous
//
#include <hip/hip_runtime.h>
#include <hip/hip_bf16.h>
#include <math.h>

// Problem constants
#define BB 4
#define CIN 64
#define DI 128       // D_INNER
#define NS 16        // D_STATE
#define HH 256
#define WW 256
#define HW 65536     // HH*WW (2^16)
#define NCH_P 33     // 1 + 2*NS

// ---------------------------------------------------------------- fast math helpers
__device__ __forceinline__ float softplusf(float x) {
    return fmaxf(x, 0.f) + __logf(1.0f + __expf(-fabsf(x)));
}
__device__ __forceinline__ float tanh_half(float a) {   // tanh(0.5*a)
    return 1.0f - 2.0f / (1.0f + __expf(a));
}
__device__ __forceinline__ float sigmoidf(float z) {
    return 1.0f / (1.0f + __expf(-z));
}

__device__ __forceinline__ void gauss15(float* g) {
    float s = 0.f;
#pragma unroll
    for (int i = 0; i < 15; ++i) {
        float a = (float)i - 7.0f;
        g[i] = __expf(-a * a / 18.0f);   // 2*sigma^2 = 18
        s += g[i];
    }
    float inv = 1.0f / s;
#pragma unroll
    for (int i = 0; i < 15; ++i) g[i] *= inv;
}

// ---------------------------------------------------------------- K1: in_proj (U half only), one batch
__global__ __launch_bounds__(256) void k_inproj(
    const float* __restrict__ xb, const float* __restrict__ w,
    const float* __restrict__ bias, float* __restrict__ Ub) {
    int p = blockIdx.x * 256 + threadIdx.x;
    int og = blockIdx.y * 64;
    float xv[CIN];
#pragma unroll
    for (int c = 0; c < CIN; ++c) xv[c] = xb[(size_t)c * HW + p];
#pragma unroll 2
    for (int o = og; o < og + 64; ++o) {
        float a0 = bias[o], a1 = 0.f, a2 = 0.f, a3 = 0.f;
        const float* wr = w + o * CIN;
#pragma unroll
        for (int c = 0; c < CIN; c += 4) {
            a0 = fmaf(xv[c],     wr[c],     a0);
            a1 = fmaf(xv[c + 1], wr[c + 1], a1);
            a2 = fmaf(xv[c + 2], wr[c + 2], a2);
            a3 = fmaf(xv[c + 3], wr[c + 3], a3);
        }
        Ub[(size_t)o * HW + p] = (a0 + a1) + (a2 + a3);
    }
}

// ---------------------------------------------------------------- K2: fused dw3x3+tanh+15x15 highpass, one batch
#define TILE_H 16
__global__ __launch_bounds__(256) void k_conv(
    const float* __restrict__ Ub, const float* __restrict__ dww,
    const float* __restrict__ dwb, float* __restrict__ Ucb) {
    __shared__ float sU[32 * 256];
    __shared__ float sC[30 * 272];
    int c  = blockIdx.x >> 4;
    int t  = blockIdx.x & 15;
    int h0 = t * TILE_H;
    int w  = threadIdx.x;

    const float* base = Ub + (size_t)c * HW;
#pragma unroll
    for (int i = 0; i < 32; ++i) {
        int hh = h0 + i - 8;
        sU[i * 256 + w] = (hh >= 0 && hh < HH) ? base[hh * WW + w] : 0.f;
    }
    __syncthreads();

    float wt[9];
#pragma unroll
    for (int i = 0; i < 9; ++i) wt[i] = dww[c * 9 + i];
    float bb = dwb[c];

#pragma unroll
    for (int i = 0; i < 30; ++i) {
        int r = h0 + i - 7;
        float v = 0.f;
        if (r >= 0 && r < HH) {
            float acc = bb;
#pragma unroll
            for (int ky = 0; ky < 3; ++ky) {
                const float* ur = sU + (i + ky) * 256;
#pragma unroll
                for (int kx = 0; kx < 3; ++kx) {
                    int ww = w + kx - 1;
                    if (ww >= 0 && ww < WW) acc = fmaf(ur[ww], wt[ky * 3 + kx], acc);
                }
            }
            v = tanh_half(acc);
        }
        sC[i * 272 + w + 7] = v;
    }
    if (w < 7) {
#pragma unroll
        for (int i = 0; i < 30; ++i) { sC[i * 272 + w] = 0.f; sC[i * 272 + w + 263] = 0.f; }
    }
    __syncthreads();

    float g[15]; gauss15(g);
#pragma unroll
    for (int i = 0; i < 30; ++i) {
        float acc = 0.f;
#pragma unroll
        for (int k = 0; k < 15; ++k) acc = fmaf(sC[i * 272 + w + k], g[k], acc);
        sU[i * 256 + w] = acc;
    }
    float* outp = Ucb + (size_t)c * HW + h0 * WW + w;
#pragma unroll
    for (int i = 0; i < TILE_H; ++i) {
        float acc = 0.f;
#pragma unroll
        for (int k = 0; k < 15; ++k) acc = fmaf(sU[(i + k) * 256 + w], g[k], acc);
        float center = sC[(i + 7) * 272 + w + 7];
        outp[i * WW] = center - acc;
    }
}

// ---------------------------------------------------------------- K5: x_proj (128 -> 33), nb batches
__global__ __launch_bounds__(256) void k_xproj(
    const float* __restrict__ Uc, const float* __restrict__ xw,
    float* __restrict__ P) {
    int p = blockIdx.x * 256 + threadIdx.x;
    int b = p >> 16;
    int rem = p & 65535;
    const float* up = Uc + (size_t)b * DI * HW + rem;
    float acc[NCH_P];
#pragma unroll
    for (int o = 0; o < NCH_P; ++o) acc[o] = 0.f;
    for (int c = 0; c < DI; ++c) {
        float u = up[(size_t)c * HW];
#pragma unroll
        for (int o = 0; o < NCH_P; ++o) acc[o] = fmaf(u, xw[o * DI + c], acc[o]);
    }
    float* pp = P + (size_t)b * NCH_P * HW + rem;
#pragma unroll
    for (int o = 0; o < NCH_P; ++o) pp[(size_t)o * HW] = acc[o];
}

// ---------------------------------------------------------------- K6: scan along W, LDS-staged u AND P, reg-prefetch
#define CW 32
__global__ __launch_bounds__(128) void k_scan_w(
    float* __restrict__ UY, const float* __restrict__ P,
    const float* __restrict__ A_log, const float* __restrict__ dtw,
    const float* __restrict__ dtb, const float* __restrict__ Dv) {
    __shared__ float sU[DI * 33];
    __shared__ float sP[CW * 36];
    int bh = blockIdx.x;
    int b = bh >> 8;
    int h = bh & 255;
    int t = threadIdx.x;                   // d

    float Av[NS];
#pragma unroll
    for (int n = 0; n < NS; ++n) Av[n] = -__expf(A_log[t * NS + n]);
    float wdt = dtw[t], bdt = dtb[t], Dd = Dv[t];
    float hS[NS];
#pragma unroll
    for (int n = 0; n < NS; ++n) hS[n] = 0.f;

    float* ubase = UY + (size_t)(b * DI) * HW + (size_t)h * WW;
    const float* prow = P + (size_t)(b * NCH_P) * HW + (size_t)h * WW;

    const int w4 = (t & 7) * 4;
    const int dbase = t >> 3;

    float4 rU[8];
    float rP[9];
#pragma unroll
    for (int p = 0; p < 8; ++p)
        rU[p] = *(const float4*)(ubase + (size_t)(dbase + p * 16) * HW + w4);
#pragma unroll
    for (int i = 0; i < 9; ++i) {
        int idx = i * 128 + t, ch = idx >> 5, wi = idx & 31;
        rP[i] = (ch < NCH_P) ? prow[(size_t)ch * HW + wi] : 0.f;
    }

    for (int w0 = 0; w0 < WW; w0 += CW) {
#pragma unroll
        for (int p = 0; p < 8; ++p) {
            float* s = sU + (dbase + p * 16) * 33 + w4;
            s[0] = rU[p].x; s[1] = rU[p].y; s[2] = rU[p].z; s[3] = rU[p].w;
        }
#pragma unroll
        for (int i = 0; i < 9; ++i) {
            int idx = i * 128 + t, ch = idx >> 5, wi = idx & 31;
            if (ch < NCH_P) sP[wi * 36 + ch] = rP[i];
        }
        __syncthreads();
        if (w0 + CW < WW) {
#pragma unroll
            for (int p = 0; p < 8; ++p)
                rU[p] = *(const float4*)(ubase + (size_t)(dbase + p * 16) * HW + w0 + CW + w4);
#pragma unroll
            for (int i = 0; i < 9; ++i) {
                int idx = i * 128 + t, ch = idx >> 5, wi = idx & 31;
                rP[i] = (ch < NCH_P) ? prow[(size_t)ch * HW + w0 + CW + wi] : 0.f;
            }
        }
#pragma unroll 2
        for (int wi = 0; wi < CW; ++wi) {
            const float* pr = sP + wi * 36;
            float4 q0 = *(const float4*)(pr);
            float4 q1 = *(const float4*)(pr + 4);
            float4 q2 = *(const float4*)(pr + 8);
            float4 q3 = *(const float4*)(pr + 12);
            float4 q4 = *(const float4*)(pr + 16);
            float4 q5 = *(const float4*)(pr + 20);
            float4 q6 = *(const float4*)(pr + 24);
            float4 q7 = *(const float4*)(pr + 28);
            float q8 = pr[32];
            float u = sU[t * 33 + wi];
            float dt = softplusf(fmaf(q0.x, wdt, bdt));
            float ud = u * dt;
            float y = Dd * u;
            float Bv[NS] = {q0.y,q0.z,q0.w,q1.x,q1.y,q1.z,q1.w,q2.x,
                            q2.y,q2.z,q2.w,q3.x,q3.y,q3.z,q3.w,q4.x};
            float Cv[NS] = {q4.y,q4.z,q4.w,q5.x,q5.y,q5.z,q5.w,q6.x,
                            q6.y,q6.z,q6.w,q7.x,q7.y,q7.z,q7.w,q8};
#pragma unroll
            for (int n = 0; n < NS; ++n) {
                float e = __expf(dt * Av[n]);
                hS[n] = fmaf(e, hS[n], ud * Bv[n]);
                y = fmaf(hS[n], Cv[n], y);
            }
            sU[t * 33 + wi] = y;
        }
        __syncthreads();
#pragma unroll
        for (int p = 0; p < 8; ++p) {
            const float* s = sU + (dbase + p * 16) * 33 + w4;
            float4 v; v.x = s[0]; v.y = s[1]; v.z = s[2]; v.w = s[3];
            *(float4*)(ubase + (size_t)(dbase + p * 16) * HW + w0 + w4) = v;
        }
        __syncthreads();
    }
}

// ---------------------------------------------------------------- K7 v2: scan along H with P shared across a d-group
// Block = 256 threads = 4 d x 64 w, covering (b, w-tile 64, d-group 4).
// P[33][64] per 2-row stage is loaded ONCE per block (9 coalesced loads/thread,
// ch = 4k+dl; ch32 by the dl==0 wave) into double-buffered LDS [ch][wl]
// (conflict-free: lanes = consecutive wl). Compute reads 33 ds_reads/row instead
// of 33 global loads -> P L2/L3 logical traffic /4 (4.4 GB -> 1.1 GB), VMEM
// issue per lane-row 34 -> ~10, vmcnt stalls replaced by barriered prefetch.
// u/y remain fully coalesced (wave = 64 consecutive w). Per-element arithmetic
// order identical to R2 (absmax check). Live regs ~75 -> allocator-safe.
// Checks: WRITE_SIZE == 131072 KB, LDS_Block_Size ~33.8 KB, bank conflicts ~0.
#define WT2 64

#define LD2(hb) { \
    _Pragma("unroll") for (int rr = 0; rr < 2; ++rr) { \
        int hp = (hb) + rr; if (hp > HH - 1) hp = HH - 1; \
        const float* pr_ = pt + hp * WW; \
        _Pragma("unroll") for (int k = 0; k < 8; ++k) rp[rr][k] = pr_[(size_t)(4 * k) * HW]; \
        rp8[rr] = (dl == 0) ? pr_[(size_t)32 * HW] : 0.f; \
    } }
#define WR2(bf) { \
    _Pragma("unroll") for (int rr = 0; rr < 2; ++rr) { \
        _Pragma("unroll") for (int k = 0; k < 8; ++k) sP[bf][rr][4 * k + dl][wl] = rp[rr][k]; \
        if (dl == 0) sP[bf][rr][32][wl] = rp8[rr]; \
    } }
#define PU2(uu, hp_) { int hp = (hp_); if (hp > HH - 1) hp = HH - 1; uu = ub[hp * WW]; }
#define CP2(bf, rr, hh, uu) { \
    const float* pr_ = &sP[bf][rr][0][wl]; \
    float de = pr_[0]; \
    float dt = softplusf(fmaf(de, wdt, bdt)); \
    float ud = (uu) * dt; \
    float y = Dd * (uu); \
    _Pragma("unroll") for (int n = 0; n < NS; ++n) { \
        float e = __expf(dt * Av[n]); \
        hS[n] = fmaf(e, hS[n], ud * pr_[(1 + n) * WT2]); \
        y = fmaf(hS[n], pr_[(17 + n) * WT2], y); } \
    ub[(hh) * WW] = y; }

__global__ __launch_bounds__(256) void k_scan_h(
    float* __restrict__ UY, const float* __restrict__ P,
    const float* __restrict__ A_log, const float* __restrict__ dtw,
    const float* __restrict__ dtb, const float* __restrict__ Dv) {
    __shared__ float sP[2][2][NCH_P][WT2];   // 33,792 B
    int bid = blockIdx.x;
    int b  = bid >> 7;          // 128 blocks per batch
    int r  = bid & 127;
    int wt = r >> 5;            // w-tile 0..3
    int dg = r & 31;            // d-group 0..31
    int t  = threadIdx.x;
    int dl = t >> 6;            // 0..3 (wave-uniform)
    int wl = t & 63;
    int d  = dg * 4 + dl;

    float Av[NS];
#pragma unroll
    for (int n = 0; n < NS; ++n) Av[n] = -__expf(A_log[d * NS + n]);
    float wdt = dtw[d], bdt = dtb[d], Dd = Dv[d];
    float hS[NS];
#pragma unroll
    for (int n = 0; n < NS; ++n) hS[n] = 0.f;

    float* ub = UY + (size_t)(b * DI + d) * HW + wt * WT2 + wl;            // + h*WW
    const float* pt = P + (size_t)b * NCH_P * HW + (size_t)dl * HW + wt * WT2 + wl; // + 4k*HW + h*WW

    float rp[2][8], rp8[2];
    float uA0, uA1, uB0, uB1;

    // prologue: rows 0,1 staged; rp <- rows 2,3; u for rows 0..3
    LD2(0);
    PU2(uA0, 0); PU2(uA1, 1); PU2(uB0, 2); PU2(uB1, 3);
    WR2(0);
    __syncthreads();
    LD2(2);

#pragma unroll 1
    for (int h0 = 0; h0 < HH; h0 += 4) {
        // sP[0] holds rows h0,h0+1; rp holds rows h0+2,h0+3
        CP2(0, 0, h0,     uA0);
        CP2(0, 1, h0 + 1, uA1);
        WR2(1);
        __syncthreads();
        LD2(h0 + 4);
        PU2(uA0, h0 + 4); PU2(uA1, h0 + 5);
        // sP[1] holds rows h0+2,h0+3; rp holds rows h0+4,h0+5
        CP2(1, 0, h0 + 2, uB0);
        CP2(1, 1, h0 + 3, uB1);
        WR2(0);
        __syncthreads();
        LD2(h0 + 6);
        PU2(uB0, h0 + 6); PU2(uB1, h0 + 7);
    }
}

// ---------------------------------------------------------------- K8a: gate in-place: Y <- Y * sigmoid(Wz x + bz)
// (R2 version verbatim — fusion with k_out2 abandoned: R1 scratch spill, R4/R6
// allocator AGPR-shuffle at VGPR 76 regardless of launch bounds.)
__global__ __launch_bounds__(256) void k_gate(
    float* __restrict__ Y, const float* __restrict__ x,
    const float* __restrict__ wz, const float* __restrict__ bz) {
    int p = blockIdx.x * 256 + threadIdx.x;
    int b = p >> 16;
    int rem = p & 65535;
    const float* xp = x + (size_t)b * CIN * HW + rem;
    float xv[CIN];
#pragma unroll
    for (int c = 0; c < CIN; ++c) xv[c] = xp[(size_t)c * HW];
    float* yp = Y + (size_t)b * DI * HW + rem;
#pragma unroll 2
    for (int dd = 0; dd < DI; ++dd) {
        float z0 = 0.f, z1 = 0.f, z2 = 0.f, z3 = 0.f;
        const float* wr = wz + dd * CIN;
#pragma unroll
        for (int c = 0; c < CIN; c += 4) {
            z0 = fmaf(xv[c],     wr[c],     z0);
            z1 = fmaf(xv[c + 1], wr[c + 1], z1);
            z2 = fmaf(xv[c + 2], wr[c + 2], z2);
            z3 = fmaf(xv[c + 3], wr[c + 3], z3);
        }
        float z = bz[dd] + ((z0 + z1) + (z2 + z3));
        float yv = yp[(size_t)dd * HW];
        yp[(size_t)dd * HW] = yv * sigmoidf(z);
    }
}

// ---------------------------------------------------------------- K8b: out = Wo * G + ob
__global__ __launch_bounds__(256) void k_out2(
    const float* __restrict__ G, const float* __restrict__ ow,
    const float* __restrict__ ob, float* __restrict__ outp) {
    int p = blockIdx.x * 256 + threadIdx.x;
    int b = p >> 16;
    int rem = p & 65535;
    const float* gp = G + (size_t)b * DI * HW + rem;
    float acc[CIN];
#pragma unroll
    for (int c = 0; c < CIN; ++c) acc[c] = 0.f;
    for (int dd = 0; dd < DI; ++dd) {
        float g = gp[(size_t)dd * HW];
#pragma unroll
        for (int c = 0; c < CIN; ++c) acc[c] = fmaf(g, ow[c * DI + dd], acc[c]);
    }
    float* op = outp + (size_t)b * CIN * HW + rem;
#pragma unroll
    for (int c = 0; c < CIN; ++c) op[(size_t)c * HW] = acc[c] + ob[c];
}

// ---------------------------------------------------------------- launch
extern "C" void kernel_launch(void* const* d_in, const int* in_sizes, int n_in,
                              void* d_out, int out_size, void* d_ws, size_t ws_size,
                              hipStream_t stream) {
    const float* x     = (const float*)d_in[0];
    const float* ipw   = (const float*)d_in[1];
    const float* ipb   = (const float*)d_in[2];
    const float* dww   = (const float*)d_in[3];
    const float* dwb   = (const float*)d_in[4];
    const float* xpw   = (const float*)d_in[5];
    const float* dtw   = (const float*)d_in[6];
    const float* dtb   = (const float*)d_in[7];
    const float* A_log = (const float*)d_in[8];
    const float* Dv    = (const float*)d_in[9];
    const float* ow    = (const float*)d_in[10];
    const float* ob    = (const float*)d_in[11];
    float* out = (float*)d_out;

    const float* wz = ipw + (size_t)DI * CIN;
    const float* bz = ipb + DI;

    const size_t PLANE = (size_t)DI * HW;
    const size_t NB    = (size_t)BB * PLANE;

    if (ws_size >= (NB + PLANE) * sizeof(float)) {
        // ---------- Path A: full-batch scans. ws = Y(4) + U(1); P staged in d_out.
        float* bufY = (float*)d_ws;
        float* bufU = bufY + NB;
        float* P    = out;
        for (int b = 0; b < BB; ++b) {
            k_inproj<<<dim3(HW / 256, 2), 256, 0, stream>>>(x + (size_t)b * CIN * HW, ipw, ipb, bufU);
            k_conv<<<DI * 16, 256, 0, stream>>>(bufU, dww, dwb, bufY + (size_t)b * PLANE);
        }
        k_xproj<<<BB * (HW / 256), 256, 0, stream>>>(bufY, xpw, P);
        k_scan_w<<<BB * HH, 128, 0, stream>>>(bufY, P, A_log, dtw, dtb, Dv);
        k_scan_h<<<BB * 128, 256, 0, stream>>>(bufY, P, A_log, dtw, dtb, Dv);
        k_gate<<<BB * (HW / 256), 256, 0, stream>>>(bufY, x, wz, bz);
        k_out2<<<BB * (HW / 256), 256, 0, stream>>>(bufY, ow, ob, out);
    } else {
        // ---------- Path B: batch-sequential. ws = U_b/P_b (overlapped) + Y_b.
        float* bufA = (float*)d_ws;
        float* bufY = bufA + PLANE;
        for (int b = 0; b < BB; ++b) {
            const float* xb = x + (size_t)b * CIN * HW;
            k_inproj<<<dim3(HW / 256, 2), 256, 0, stream>>>(xb, ipw, ipb, bufA);
            k_conv<<<DI * 16, 256, 0, stream>>>(bufA, dww, dwb, bufY);
            k_xproj<<<HW / 256, 256, 0, stream>>>(bufY, xpw, bufA);
            k_scan_w<<<HH, 128, 0, stream>>>(bufY, bufA, A_log, dtw, dtb, Dv);
            k_scan_h<<<128, 256, 0, stream>>>(bufY, bufA, A_log, dtw, dtb, Dv);
            k_gate<<<HW / 256, 256, 0, stream>>>(bufY, xb, wz, bz);
            k_out2<<<HW / 256, 256, 0, stream>>>(bufY, ow, ob, out + (size_t)b * CIN * HW);
        }
    }
}